// Round 9
// baseline (550.326 us; speedup 1.0000x reference)
//
#include <hip/hip_runtime.h>
#include <math.h>

#define BSZ  64
#define NSEQ 512
#define FEAT 64
#define HID  128
#define NITER 3
#define RTOT (BSZ*NSEQ)   // 32768 rows
#define LDAP 136          // padded LDS plane stride (shorts)

typedef __attribute__((ext_vector_type(8))) short bf16x8;
typedef __attribute__((ext_vector_type(4))) float f32x4;
typedef unsigned int u32;

// ---------------- helpers ----------------

__device__ __forceinline__ float sigm(float v) {
  v = fminf(fmaxf(v, -30.f), 30.f);
  return 1.0f / (1.0f + __expf(-v));
}
__device__ __forceinline__ float tanh_fast(float v) {
  v = fminf(fmaxf(v, -15.f), 15.f);
  float e = __expf(2.0f * v);
  return (e - 1.0f) / (e + 1.0f);
}

// split fp32 into (hi,lo) bf16 pair packed in one u32: a ~= f(hi) + f(lo)
__device__ __forceinline__ u32 pack_split(float a) {
  u32 ub = __float_as_uint(a);
  u32 hi = ub >> 16;
  float res = a - __uint_as_float(hi << 16);
  u32 lo = __float_as_uint(res) >> 16;
  return (hi << 16) | lo;
}
__device__ __forceinline__ float bf2f(short v) {
  return __uint_as_float(((u32)(unsigned short)v) << 16);
}

// 3-term split-bf16 product: ah*bh + ah*bl + al*bh
__device__ __forceinline__ f32x4 mfma3(bf16x8 ah, bf16x8 al, bf16x8 bh, bf16x8 bl, f32x4 c) {
  c = __builtin_amdgcn_mfma_f32_16x16x32_bf16(ah, bh, c, 0, 0, 0);
  c = __builtin_amdgcn_mfma_f32_16x16x32_bf16(ah, bl, c, 0, 0, 0);
  c = __builtin_amdgcn_mfma_f32_16x16x32_bf16(al, bh, c, 0, 0, 0);
  return c;
}

// stage packed-u32 [64][128] global tile -> two LDS short planes [64][LDAP]
__device__ __forceinline__ void stage_planes(const u32* __restrict__ g, short* hiP, short* loP, int t) {
  const int row = t >> 3, col = (t & 7) * 16;
  const u32* src = g + (size_t)row * HID + col;
  #pragma unroll
  for (int i = 0; i < 4; ++i) {
    uint4 u = *(const uint4*)(src + i * 4);
    *(short4*)&hiP[row * LDAP + col + i * 4] =
        make_short4((short)(u.x >> 16), (short)(u.y >> 16), (short)(u.z >> 16), (short)(u.w >> 16));
    *(short4*)&loP[row * LDAP + col + i * 4] =
        make_short4((short)(u.x & 0xffff), (short)(u.y & 0xffff), (short)(u.z & 0xffff), (short)(u.w & 0xffff));
  }
}

// one full 128-K gate. A from LDS planes P[AP],P[AP+1]; B from FRAGMENT-BLOCKED
// global weights: per (ks,nh,nt) a contiguous [64][8] hi block then [64][8] lo.
// offset(shorts) = ((ks*2 + nh)*4 + nt)*1024 + plane*512 + l*8
#define GATE(ACC, AP, WB) do { \
  _Pragma("unroll") \
  for (int ks_ = 0; ks_ < 4; ++ks_) { \
    bf16x8 ah_ = *(bf16x8*)&P[AP][lrow][ks_*32 + kgrp]; \
    bf16x8 al_ = *(bf16x8*)&P[(AP)+1][lrow][ks_*32 + kgrp]; \
    _Pragma("unroll") \
    for (int nt_ = 0; nt_ < 4; ++nt_) { \
      const short* fb_ = (WB) + (((ks_*2 + nh)*4 + nt_) * 1024) + l * 8; \
      bf16x8 bh_ = *(const bf16x8*)fb_; \
      bf16x8 bl_ = *(const bf16x8*)(fb_ + 512); \
      ACC[nt_] = mfma3(ah_, al_, bh_, bl_, ACC[nt_]); \
    } \
  } \
} while (0)

__device__ __forceinline__ void micro4(const float4 a, const float4 b0, const float4 b1,
                                       const float4 b2, const float4 b3, float acc[4]) {
  acc[0] = fmaf(a.x, b0.x, acc[0]); acc[0] = fmaf(a.y, b1.x, acc[0]);
  acc[0] = fmaf(a.z, b2.x, acc[0]); acc[0] = fmaf(a.w, b3.x, acc[0]);
  acc[1] = fmaf(a.x, b0.y, acc[1]); acc[1] = fmaf(a.y, b1.y, acc[1]);
  acc[1] = fmaf(a.z, b2.y, acc[1]); acc[1] = fmaf(a.w, b3.y, acc[1]);
  acc[2] = fmaf(a.x, b0.z, acc[2]); acc[2] = fmaf(a.y, b1.z, acc[2]);
  acc[2] = fmaf(a.z, b2.z, acc[2]); acc[2] = fmaf(a.w, b3.z, acc[2]);
  acc[3] = fmaf(a.x, b0.w, acc[3]); acc[3] = fmaf(a.y, b1.w, acc[3]);
  acc[3] = fmaf(a.z, b2.w, acc[3]); acc[3] = fmaf(a.w, b3.w, acc[3]);
}

// ---------------- kernels ----------------

// one-time: split the 21 [128][128] weight mats -> fragment-blocked bf16 hi/lo planes.
__global__ __launch_bounds__(256) void k_prep(
    const float* __restrict__ Wm, const float* __restrict__ Wz, const float* __restrict__ Uz,
    const float* __restrict__ Wr, const float* __restrict__ Ur, const float* __restrict__ Wh,
    const float* __restrict__ Uh, short* __restrict__ wpl) {
  __shared__ float Wl[HID * HID];   // 64KB
  const int t = threadIdx.x;
  const int m = blockIdx.x;        // 0..20
  const int g = m / 3, it = m - g * 3;
  const float* src;
  switch (g) { case 0: src = Wm; break; case 1: src = Wz; break; case 2: src = Uz; break;
               case 3: src = Wr; break; case 4: src = Ur; break; case 5: src = Wh; break;
               default: src = Uh; }
  src += (size_t)it * HID * HID;
  for (int i = t; i < HID * HID / 4; i += 256) ((float4*)Wl)[i] = ((const float4*)src)[i];
  __syncthreads();
  short* dst = wpl + (size_t)m * 32768;
  for (int s = t; s < 2048; s += 256) {
    const int lane = s & 63;
    const int blk = s >> 6;            // (ks*2+nh)*4+nt, 0..31
    const int nt = blk & 3;
    const int nh = (blk >> 2) & 1;
    const int ks = blk >> 3;
    const int n = nh * 64 + nt * 16 + (lane & 15);
    const int k0 = ks * 32 + (lane >> 4) * 8;
    short h8[8], l8[8];
    #pragma unroll
    for (int j = 0; j < 8; ++j) {
      u32 pk = pack_split(Wl[(size_t)(k0 + j) * HID + n]);
      h8[j] = (short)(pk >> 16);
      l8[j] = (short)(pk & 0xffff);
    }
    short* o = dst + blk * 1024 + lane * 8;
    *(bf16x8*)o = *(bf16x8*)h8;
    *(bf16x8*)(o + 512) = *(bf16x8*)l8;
  }
}

// h = relu(x @ W_emb + b_emb) + pos_table[:n] -> packed u32 (fp32 compute, runs once)
__global__ __launch_bounds__(256) void k_embed(const float* __restrict__ x, const float* __restrict__ W,
                                               const float* __restrict__ bias, const float* __restrict__ pos,
                                               u32* __restrict__ hP) {
  __shared__ float xs[32][FEAT];
  const int t = threadIdx.x;
  const int row0 = blockIdx.x * 32;
  {
    const float4* xv = (const float4*)(x + (size_t)row0 * FEAT);
    float4* xd = (float4*)&xs[0][0];
    for (int i = t; i < 32 * FEAT / 4; i += 256) xd[i] = xv[i];
  }
  __syncthreads();
  const int c0 = (t & 31) * 4;
  const int r0 = (t >> 5) * 4;
  float acc[4][4] = {};
  #pragma unroll 2
  for (int k = 0; k < FEAT; k += 4) {
    float4 b0 = *(const float4*)&W[(k + 0) * HID + c0];
    float4 b1 = *(const float4*)&W[(k + 1) * HID + c0];
    float4 b2 = *(const float4*)&W[(k + 2) * HID + c0];
    float4 b3 = *(const float4*)&W[(k + 3) * HID + c0];
    float4 a0 = *(const float4*)&xs[r0 + 0][k];
    float4 a1 = *(const float4*)&xs[r0 + 1][k];
    float4 a2 = *(const float4*)&xs[r0 + 2][k];
    float4 a3 = *(const float4*)&xs[r0 + 3][k];
    micro4(a0, b0, b1, b2, b3, acc[0]);
    micro4(a1, b0, b1, b2, b3, acc[1]);
    micro4(a2, b0, b1, b2, b3, acc[2]);
    micro4(a3, b0, b1, b2, b3, acc[3]);
  }
  const float4 bv = *(const float4*)&bias[c0];
  #pragma unroll
  for (int r = 0; r < 4; ++r) {
    const int row = row0 + r0 + r;
    const int n = row & (NSEQ - 1);
    const float4 pv = *(const float4*)&pos[(size_t)n * HID + c0];
    uint4 pk;
    pk.x = pack_split(fmaxf(acc[r][0] + bv.x, 0.f) + pv.x);
    pk.y = pack_split(fmaxf(acc[r][1] + bv.y, 0.f) + pv.y);
    pk.z = pack_split(fmaxf(acc[r][2] + bv.z, 0.f) + pv.z);
    pk.w = pack_split(fmaxf(acc[r][3] + bv.w, 0.f) + pv.w);
    *(uint4*)&hP[(size_t)row * HID + c0] = pk;
  }
}

__global__ __launch_bounds__(256) void k_sinit(float* __restrict__ s) {
  const int i = blockIdx.x * 256 + threadIdx.x;
  if (i < RTOT) {
    const int n = i & (NSEQ - 1);
    s[(size_t)i * 3 + 0] = ((float)n - (NSEQ - 1) * 0.5f) / (float)NSEQ;
    s[(size_t)i * 3 + 1] = 0.f;
    s[(size_t)i * 3 + 2] = 0.f;
  }
}

// m = relu(h @ Wm + bm) -> FRAGMENT-BLOCKED bf16 planes for k_agg:
// mtB[b][jt(16)][nh(2)][nt(4)][plane(2)][64][8]
__global__ __launch_bounds__(512) void k_msg(const u32* __restrict__ hP, const short* __restrict__ wpl,
                                             int iter, const float* __restrict__ bm,
                                             short* __restrict__ mtB) {
  __shared__ short P[2][64][LDAP];   // h hi/lo planes
  __shared__ short T[2][128][72];    // transpose buffer [n][j-local]
  const int t = threadIdx.x;
  const int row0 = blockIdx.x * 64;
  stage_planes(hP + (size_t)row0 * HID, &P[0][0][0], &P[1][0][0], t);
  __syncthreads();
  const int l = t & 63, w = t >> 6;
  const int mt = w & 3, nh = w >> 2;
  const int lrow = mt * 16 + (l & 15);
  const int kgrp = (l >> 4) * 8;
  const int ncol = l & 15;
  f32x4 z4 = {0.f, 0.f, 0.f, 0.f};
  f32x4 acc[4];
  #pragma unroll
  for (int i = 0; i < 4; ++i) acc[i] = z4;
  GATE(acc, 0, wpl + (size_t)(0 * 3 + iter) * 32768);
  const int rbase = mt * 16 + (l >> 4) * 4;
  #pragma unroll
  for (int nt = 0; nt < 4; ++nt) {
    const int cc = nh * 64 + nt * 16 + ncol;
    const float bmc = bm[cc];
    #pragma unroll
    for (int q = 0; q < 4; ++q) {
      u32 pk = pack_split(fmaxf(acc[nt][q] + bmc, 0.f));
      T[0][cc][rbase + q] = (short)(pk >> 16);
      T[1][cc][rbase + q] = (short)(pk & 0xffff);
    }
  }
  __syncthreads();
  const int b = row0 >> 9, j0 = row0 & (NSEQ - 1);
  const int n = t >> 2, jq = (t & 3) * 16;
  const int nh2 = n >> 6, nt2 = (n >> 4) & 3;
  #pragma unroll
  for (int gch = 0; gch < 2; ++gch) {          // two 8-j groups
    const int jj = jq + gch * 8;               // 0..63 local
    const int jt = (j0 + jj) >> 5;             // global j-tile
    const int jjj = (j0 + jj) & 31;
    const int lane = (jjj >> 3) * 16 + (n & 15);
    #pragma unroll
    for (int pl = 0; pl < 2; ++pl) {
      size_t off = ((((((size_t)b * 16 + jt) * 2 + nh2) * 4 + nt2) * 2 + pl) * 64 + lane) * 8;
      *(bf16x8*)&mtB[off] = *(bf16x8*)&T[pl][n][jj];
    }
  }
}

// agg = (exp(-100 d2)*mask) @ m. Register-direct A, NO exp duplication (each
// wave covers full n=128, 64 i-rows/block), and a 4-tile-deep mask prefetch
// pipeline so HBM latency hides under exp+MFMA of the current group.
__global__ __launch_bounds__(256) void k_agg(const float* __restrict__ s, const float* __restrict__ mask,
                                             const short* __restrict__ mtB, u32* __restrict__ aggP) {
  __shared__ float sj4[NSEQ][4];   // 8KB: x,y,z,pad  (one ds_read_b128 per j)
  const int t = threadIdx.x;
  const int b = blockIdx.x;
  const int i0 = blockIdx.y * 64;
  {
    const float* sp = s + (size_t)b * NSEQ * 3;
    for (int i = t; i < NSEQ; i += 256) {
      sj4[i][0] = sp[i * 3 + 0];
      sj4[i][1] = sp[i * 3 + 1];
      sj4[i][2] = sp[i * 3 + 2];
      sj4[i][3] = 0.f;
    }
  }
  __syncthreads();
  const int l = t & 63, w = t >> 6;            // 4 waves, each a 16-row i-quadrant
  const int kgrp = (l >> 4) * 8, ncol = l & 15;
  const int arow = w * 16 + (l & 15);          // local i-row whose A-frag this lane builds
  const float six = sj4[i0 + arow][0], siy = sj4[i0 + arow][1], siz = sj4[i0 + arow][2];
  const float* mrow = mask + ((size_t)b * NSEQ + i0 + arow) * NSEQ;
  f32x4 z4 = {0.f, 0.f, 0.f, 0.f};
  f32x4 acc[8];
  #pragma unroll
  for (int i = 0; i < 8; ++i) acc[i] = z4;
  const short* mtb = mtB + (size_t)b * 131072;

  // prologue: masks for tiles 0..3
  float4 c[8];
  #pragma unroll
  for (int k = 0; k < 4; ++k) {
    c[2 * k]     = *(const float4*)&mrow[k * 32 + kgrp];
    c[2 * k + 1] = *(const float4*)&mrow[k * 32 + kgrp + 4];
  }
  #pragma unroll 1
  for (int jg = 0; jg < 4; ++jg) {
    float4 nx[8];
    if (jg < 3) {   // issue next group's mask loads BEFORE computing this group
      const int nb = (jg + 1) * 128;
      #pragma unroll
      for (int k = 0; k < 4; ++k) {
        nx[2 * k]     = *(const float4*)&mrow[nb + k * 32 + kgrp];
        nx[2 * k + 1] = *(const float4*)&mrow[nb + k * 32 + kgrp + 4];
      }
    }
    #pragma unroll
    for (int k = 0; k < 4; ++k) {
      const int jt = jg * 4 + k;
      const int j0 = jt * 32 + kgrp;
      const float mv[8] = {c[2*k].x, c[2*k].y, c[2*k].z, c[2*k].w,
                           c[2*k+1].x, c[2*k+1].y, c[2*k+1].z, c[2*k+1].w};
      short ha[8], la[8];
      #pragma unroll
      for (int j = 0; j < 8; ++j) {
        const float4 sv = *(const float4*)&sj4[j0 + j][0];
        const float dx = six - sv.x, dy = siy - sv.y, dz = siz - sv.z;
        const float d2 = dx * dx + dy * dy + dz * dz;
        const u32 pk = pack_split(__expf(-100.0f * d2) * mv[j]);
        ha[j] = (short)(pk >> 16);
        la[j] = (short)(pk & 0xffff);
      }
      const bf16x8 ah = *(bf16x8*)ha;
      const bf16x8 al = *(bf16x8*)la;
      #pragma unroll
      for (int n2 = 0; n2 < 8; ++n2) {
        const short* fb = mtb + ((((size_t)jt * 2 + (n2 >> 2)) * 4 + (n2 & 3)) * 2) * 512 + l * 8;
        acc[n2] = mfma3(ah, al, *(const bf16x8*)fb, *(const bf16x8*)(fb + 512), acc[n2]);
      }
    }
    if (jg < 3) {
      #pragma unroll
      for (int q = 0; q < 8; ++q) c[q] = nx[q];
    }
  }
  #pragma unroll
  for (int n2 = 0; n2 < 8; ++n2) {
    const int cc = (n2 >> 2) * 64 + (n2 & 3) * 16 + ncol;
    #pragma unroll
    for (int q = 0; q < 4; ++q) {
      const int grow = i0 + w * 16 + (l >> 4) * 4 + q;
      aggP[((size_t)b * NSEQ + grow) * HID + cc] = pack_split(acc[n2][q]);
    }
  }
}

// fused GRU: 6 gates, rh computed mid-kernel into the h LDS planes. 3 barriers.
__global__ __launch_bounds__(512) void k_zrc(
    const u32* __restrict__ aggP, u32* __restrict__ hP,
    const short* __restrict__ wpl, int iter,
    const float* __restrict__ bz, const float* __restrict__ br, const float* __restrict__ bhh) {
  __shared__ short P[4][64][LDAP];   // 0,1: agg hi/lo; 2,3: h hi/lo (later rh hi/lo)
  const int t = threadIdx.x;
  const int row0 = blockIdx.x * 64;
  stage_planes(aggP + (size_t)row0 * HID, &P[0][0][0], &P[1][0][0], t);
  stage_planes(hP + (size_t)row0 * HID, &P[2][0][0], &P[3][0][0], t);
  __syncthreads();
  const int l = t & 63, w = t >> 6;
  const int mt = w & 3, nh = w >> 2;
  const int lrow = mt * 16 + (l & 15);
  const int kgrp = (l >> 4) * 8;
  const int ncol = l & 15;
  f32x4 z4 = {0.f, 0.f, 0.f, 0.f};
  f32x4 accz[4], accr[4];
  #pragma unroll
  for (int i = 0; i < 4; ++i) { accz[i] = z4; accr[i] = z4; }
  #pragma unroll 1
  for (int g = 0; g < 4; ++g) {   // Wz(agg), Uz(h), Wr(agg), Ur(h)
    const short* WB = wpl + (size_t)((g + 1) * 3 + iter) * 32768;
    const int ap = (g & 1) * 2;
    if (g < 2) { GATE(accz, ap, WB); }
    else       { GATE(accr, ap, WB); }
  }
  const int rbase = mt * 16 + (l >> 4) * 4;
  float hreg[4][4];
  float rhv[4][4];
  #pragma unroll
  for (int nt = 0; nt < 4; ++nt) {
    const int cc = nh * 64 + nt * 16 + ncol;
    const float brc = br[cc];
    #pragma unroll
    for (int q = 0; q < 4; ++q) {
      float hv = bf2f(P[2][rbase + q][cc]) + bf2f(P[3][rbase + q][cc]);
      hreg[nt][q] = hv;
      rhv[nt][q] = sigm(accr[nt][q] + brc) * hv;
    }
  }
  __syncthreads();   // all gates done reading h planes
  #pragma unroll
  for (int nt = 0; nt < 4; ++nt) {
    const int cc = nh * 64 + nt * 16 + ncol;
    #pragma unroll
    for (int q = 0; q < 4; ++q) {
      u32 pk = pack_split(rhv[nt][q]);
      P[2][rbase + q][cc] = (short)(pk >> 16);
      P[3][rbase + q][cc] = (short)(pk & 0xffff);
    }
  }
  __syncthreads();   // rh planes ready
  #pragma unroll
  for (int i = 0; i < 4; ++i) accr[i] = z4;   // reuse as cand accumulator
  GATE(accr, 0, wpl + (size_t)(5 * 3 + iter) * 32768);   // Wh (A=agg)
  GATE(accr, 2, wpl + (size_t)(6 * 3 + iter) * 32768);   // Uh (A=rh)
  #pragma unroll
  for (int nt = 0; nt < 4; ++nt) {
    const int cc = nh * 64 + nt * 16 + ncol;
    const float bzc = bz[cc], bhc = bhh[cc];
    #pragma unroll
    for (int q = 0; q < 4; ++q) {
      float z = sigm(accz[nt][q] + bzc);
      float cand = tanh_fast(accr[nt][q] + bhc);
      float hn = (1.f - z) * hreg[nt][q] + z * cand;
      hP[(size_t)(row0 + rbase + q) * HID + cc] = pack_split(hn);
    }
  }
}

// positional GRU on packed h
__global__ __launch_bounds__(256) void k_posgru(const u32* __restrict__ hP, float* __restrict__ s,
    const float* __restrict__ Wpz, const float* __restrict__ Upz, const float* __restrict__ bpz,
    const float* __restrict__ Wpr, const float* __restrict__ Upr, const float* __restrict__ bpr,
    const float* __restrict__ Wph, const float* __restrict__ Uph, const float* __restrict__ bph) {
  const int lane = threadIdx.x & 63;
  const int w = threadIdx.x >> 6;
  const int row = blockIdx.x * 4 + w;
  const int k0 = lane * 2;
  const uint2 hv2 = *(const uint2*)&hP[(size_t)row * HID + k0];
  const float hx = bf2f((short)(hv2.x >> 16)) + bf2f((short)(hv2.x & 0xffff));
  const float hy = bf2f((short)(hv2.y >> 16)) + bf2f((short)(hv2.y & 0xffff));
  float p[9];
  #pragma unroll
  for (int c = 0; c < 3; ++c) {
    p[c]     = hx * Wpz[k0 * 3 + c] + hy * Wpz[(k0 + 1) * 3 + c];
    p[3 + c] = hx * Wpr[k0 * 3 + c] + hy * Wpr[(k0 + 1) * 3 + c];
    p[6 + c] = hx * Wph[k0 * 3 + c] + hy * Wph[(k0 + 1) * 3 + c];
  }
  #pragma unroll
  for (int off = 32; off > 0; off >>= 1) {
    #pragma unroll
    for (int q = 0; q < 9; ++q) p[q] += __shfl_xor(p[q], off, 64);
  }
  const float s0 = s[(size_t)row * 3 + 0], s1 = s[(size_t)row * 3 + 1], s2 = s[(size_t)row * 3 + 2];
  float zs[3], rs[3], ss[3];
  #pragma unroll
  for (int c = 0; c < 3; ++c) {
    zs[c] = sigm(p[c]     + s0 * Upz[c] + s1 * Upz[3 + c] + s2 * Upz[6 + c] + bpz[c]);
    rs[c] = sigm(p[3 + c] + s0 * Upr[c] + s1 * Upr[3 + c] + s2 * Upr[6 + c] + bpr[c]);
  }
  const float t0 = rs[0] * s0, t1 = rs[1] * s1, t2 = rs[2] * s2;
  #pragma unroll
  for (int c = 0; c < 3; ++c)
    ss[c] = tanh_fast(p[6 + c] + t0 * Uph[c] + t1 * Uph[3 + c] + t2 * Uph[6 + c] + bph[c]);
  if (lane == 0) {
    s[(size_t)row * 3 + 0] = (1.f - zs[0]) * s0 + zs[0] * ss[0];
    s[(size_t)row * 3 + 1] = (1.f - zs[1]) * s1 + zs[1] * ss[1];
    s[(size_t)row * 3 + 2] = (1.f - zs[2]) * s2 + zs[2] * ss[2];
  }
}

// A[b,i,j] = exp(-100*||s_i-s_j||^2)*mask
__global__ __launch_bounds__(256) void k_finalA(const float* __restrict__ s, const float* __restrict__ mask,
                                                float* __restrict__ A) {
  __shared__ float sj[NSEQ][3];
  const int t = threadIdx.x;
  const int b = blockIdx.x;
  const int i0 = blockIdx.y * 16;
  {
    const float* sp = s + (size_t)b * NSEQ * 3;
    for (int i = t; i < NSEQ * 3; i += 256) (&sj[0][0])[i] = sp[i];
  }
  __syncthreads();
  #pragma unroll
  for (int p = 0; p < 8; ++p) {
    const int e = t + p * 256;
    const int ii = e >> 7;
    const int j4 = (e & 127) * 4;
    const float six = sj[i0 + ii][0], siy = sj[i0 + ii][1], siz = sj[i0 + ii][2];
    const size_t base = ((size_t)b * NSEQ + i0 + ii) * NSEQ + j4;
    const float4 mk = *(const float4*)&mask[base];
    float4 o;
    { float dx = six - sj[j4+0][0], dy = siy - sj[j4+0][1], dz = siz - sj[j4+0][2];
      o.x = __expf(-100.0f*(dx*dx + dy*dy + dz*dz)) * mk.x; }
    { float dx = six - sj[j4+1][0], dy = siy - sj[j4+1][1], dz = siz - sj[j4+1][2];
      o.y = __expf(-100.0f*(dx*dx + dy*dy + dz*dz)) * mk.y; }
    { float dx = six - sj[j4+2][0], dy = siy - sj[j4+2][1], dz = siz - sj[j4+2][2];
      o.z = __expf(-100.0f*(dx*dx + dy*dy + dz*dz)) * mk.z; }
    { float dx = six - sj[j4+3][0], dy = siy - sj[j4+3][1], dz = siz - sj[j4+3][2];
      o.w = __expf(-100.0f*(dx*dx + dy*dy + dz*dz)) * mk.w; }
    *(float4*)&A[base] = o;
  }
}

// ---------------- launcher ----------------

extern "C" void kernel_launch(void* const* d_in, const int* in_sizes, int n_in,
                              void* d_out, int out_size, void* d_ws, size_t ws_size,
                              hipStream_t stream) {
  const float* x      = (const float*)d_in[0];
  const float* mask   = (const float*)d_in[1];
  const float* W_emb  = (const float*)d_in[2];
  const float* b_emb  = (const float*)d_in[3];
  const float* pos    = (const float*)d_in[4];
  const float* Wm     = (const float*)d_in[5];
  const float* bm     = (const float*)d_in[6];
  const float* Wz     = (const float*)d_in[7];
  const float* Uz     = (const float*)d_in[8];
  const float* bz     = (const float*)d_in[9];
  const float* Wr     = (const float*)d_in[10];
  const float* Ur     = (const float*)d_in[11];
  const float* br     = (const float*)d_in[12];
  const float* Wh     = (const float*)d_in[13];
  const float* Uh     = (const float*)d_in[14];
  const float* bh     = (const float*)d_in[15];
  const float* Wpz    = (const float*)d_in[16];
  const float* Upz    = (const float*)d_in[17];
  const float* bpz    = (const float*)d_in[18];
  const float* Wpr    = (const float*)d_in[19];
  const float* Upr    = (const float*)d_in[20];
  const float* bpr    = (const float*)d_in[21];
  const float* Wph    = (const float*)d_in[22];
  const float* Uph    = (const float*)d_in[23];
  const float* bph    = (const float*)d_in[24];

  u32*   hP = (u32*)d_ws;
  float* s  = (float*)d_ws + (size_t)RTOT * HID;
  float* ob   = (float*)d_out;
  u32*   aggP = (u32*)ob;                                   // 16.8MB
  short* mtB  = (short*)(ob + (size_t)RTOT * HID);          // 16.8MB (blocked m)
  short* wpl  = mtB + (size_t)BSZ * 131072;                 // 1.4MB (blocked weights)

  k_prep<<<21, 256, 0, stream>>>(Wm, Wz, Uz, Wr, Ur, Wh, Uh, wpl);
  k_embed<<<RTOT / 32, 256, 0, stream>>>(x, W_emb, b_emb, pos, hP);
  k_sinit<<<RTOT / 256, 256, 0, stream>>>(s);

  for (int i = 0; i < NITER; ++i) {
    const size_t bo = (size_t)i * HID;
    k_msg<<<RTOT / 64, 512, 0, stream>>>(hP, wpl, i, bm + bo, mtB);
    k_agg<<<dim3(BSZ, NSEQ / 64), 256, 0, stream>>>(s, mask, mtB, aggP);
    k_zrc<<<RTOT / 64, 512, 0, stream>>>(aggP, hP, wpl, i, bz + bo, br + bo, bh + bo);
    k_posgru<<<RTOT / 4, 256, 0, stream>>>(hP, s, Wpz, Upz, bpz, Wpr, Upr, bpr, Wph, Uph, bph);
  }
  k_finalA<<<dim3(BSZ, NSEQ / 16), 256, 0, stream>>>(s, mask, (float*)d_out);
}

// Round 10
// 473.214 us; speedup vs baseline: 1.1630x; 1.1630x over previous
//
#include <hip/hip_runtime.h>
#include <math.h>

#define BSZ  64
#define NSEQ 512
#define FEAT 64
#define HID  128
#define NITER 3
#define RTOT (BSZ*NSEQ)   // 32768 rows
#define LDAP 136          // padded LDS plane stride (shorts)

typedef __attribute__((ext_vector_type(8))) short bf16x8;
typedef __attribute__((ext_vector_type(4))) float f32x4;
typedef unsigned int u32;

// ---------------- helpers ----------------

__device__ __forceinline__ float sigm(float v) {
  v = fminf(fmaxf(v, -30.f), 30.f);
  return 1.0f / (1.0f + __expf(-v));
}
__device__ __forceinline__ float tanh_fast(float v) {
  v = fminf(fmaxf(v, -15.f), 15.f);
  float e = __expf(2.0f * v);
  return (e - 1.0f) / (e + 1.0f);
}

// split fp32 into (hi,lo) bf16 pair packed in one u32: a ~= f(hi) + f(lo)
__device__ __forceinline__ u32 pack_split(float a) {
  u32 ub = __float_as_uint(a);
  u32 hi = ub >> 16;
  float res = a - __uint_as_float(hi << 16);
  u32 lo = __float_as_uint(res) >> 16;
  return (hi << 16) | lo;
}
__device__ __forceinline__ float bf2f(short v) {
  return __uint_as_float(((u32)(unsigned short)v) << 16);
}

// 3-term split-bf16 product: ah*bh + ah*bl + al*bh
__device__ __forceinline__ f32x4 mfma3(bf16x8 ah, bf16x8 al, bf16x8 bh, bf16x8 bl, f32x4 c) {
  c = __builtin_amdgcn_mfma_f32_16x16x32_bf16(ah, bh, c, 0, 0, 0);
  c = __builtin_amdgcn_mfma_f32_16x16x32_bf16(ah, bl, c, 0, 0, 0);
  c = __builtin_amdgcn_mfma_f32_16x16x32_bf16(al, bh, c, 0, 0, 0);
  return c;
}

// stage packed-u32 [64][128] global tile -> two LDS short planes [64][LDAP]
__device__ __forceinline__ void stage_planes(const u32* __restrict__ g, short* hiP, short* loP, int t) {
  const int row = t >> 3, col = (t & 7) * 16;
  const u32* src = g + (size_t)row * HID + col;
  #pragma unroll
  for (int i = 0; i < 4; ++i) {
    uint4 u = *(const uint4*)(src + i * 4);
    *(short4*)&hiP[row * LDAP + col + i * 4] =
        make_short4((short)(u.x >> 16), (short)(u.y >> 16), (short)(u.z >> 16), (short)(u.w >> 16));
    *(short4*)&loP[row * LDAP + col + i * 4] =
        make_short4((short)(u.x & 0xffff), (short)(u.y & 0xffff), (short)(u.z & 0xffff), (short)(u.w & 0xffff));
  }
}

// one full 128-K gate. A from LDS planes P[AP],P[AP+1]; B from FRAGMENT-BLOCKED
// global weights: per (ks,nh,nt) a contiguous [64][8] hi block then [64][8] lo.
#define GATE(ACC, AP, WB) do { \
  _Pragma("unroll") \
  for (int ks_ = 0; ks_ < 4; ++ks_) { \
    bf16x8 ah_ = *(bf16x8*)&P[AP][lrow][ks_*32 + kgrp]; \
    bf16x8 al_ = *(bf16x8*)&P[(AP)+1][lrow][ks_*32 + kgrp]; \
    _Pragma("unroll") \
    for (int nt_ = 0; nt_ < 4; ++nt_) { \
      const short* fb_ = (WB) + (((ks_*2 + nh)*4 + nt_) * 1024) + l * 8; \
      bf16x8 bh_ = *(const bf16x8*)fb_; \
      bf16x8 bl_ = *(const bf16x8*)(fb_ + 512); \
      ACC[nt_] = mfma3(ah_, al_, bh_, bl_, ACC[nt_]); \
    } \
  } \
} while (0)

__device__ __forceinline__ void micro4(const float4 a, const float4 b0, const float4 b1,
                                       const float4 b2, const float4 b3, float acc[4]) {
  acc[0] = fmaf(a.x, b0.x, acc[0]); acc[0] = fmaf(a.y, b1.x, acc[0]);
  acc[0] = fmaf(a.z, b2.x, acc[0]); acc[0] = fmaf(a.w, b3.x, acc[0]);
  acc[1] = fmaf(a.x, b0.y, acc[1]); acc[1] = fmaf(a.y, b1.y, acc[1]);
  acc[1] = fmaf(a.z, b2.y, acc[1]); acc[1] = fmaf(a.w, b3.y, acc[1]);
  acc[2] = fmaf(a.x, b0.z, acc[2]); acc[2] = fmaf(a.y, b1.z, acc[2]);
  acc[2] = fmaf(a.z, b2.z, acc[2]); acc[2] = fmaf(a.w, b3.z, acc[2]);
  acc[3] = fmaf(a.x, b0.w, acc[3]); acc[3] = fmaf(a.y, b1.w, acc[3]);
  acc[3] = fmaf(a.z, b2.w, acc[3]); acc[3] = fmaf(a.w, b3.w, acc[3]);
}

// ---------------- kernels ----------------

// one-time: split the 21 [128][128] weight mats -> fragment-blocked bf16 hi/lo planes.
__global__ __launch_bounds__(256) void k_prep(
    const float* __restrict__ Wm, const float* __restrict__ Wz, const float* __restrict__ Uz,
    const float* __restrict__ Wr, const float* __restrict__ Ur, const float* __restrict__ Wh,
    const float* __restrict__ Uh, short* __restrict__ wpl) {
  __shared__ float Wl[HID * HID];   // 64KB
  const int t = threadIdx.x;
  const int m = blockIdx.x;        // 0..20
  const int g = m / 3, it = m - g * 3;
  const float* src;
  switch (g) { case 0: src = Wm; break; case 1: src = Wz; break; case 2: src = Uz; break;
               case 3: src = Wr; break; case 4: src = Ur; break; case 5: src = Wh; break;
               default: src = Uh; }
  src += (size_t)it * HID * HID;
  for (int i = t; i < HID * HID / 4; i += 256) ((float4*)Wl)[i] = ((const float4*)src)[i];
  __syncthreads();
  short* dst = wpl + (size_t)m * 32768;
  for (int s = t; s < 2048; s += 256) {
    const int lane = s & 63;
    const int blk = s >> 6;            // (ks*2+nh)*4+nt, 0..31
    const int nt = blk & 3;
    const int nh = (blk >> 2) & 1;
    const int ks = blk >> 3;
    const int n = nh * 64 + nt * 16 + (lane & 15);
    const int k0 = ks * 32 + (lane >> 4) * 8;
    short h8[8], l8[8];
    #pragma unroll
    for (int j = 0; j < 8; ++j) {
      u32 pk = pack_split(Wl[(size_t)(k0 + j) * HID + n]);
      h8[j] = (short)(pk >> 16);
      l8[j] = (short)(pk & 0xffff);
    }
    short* o = dst + blk * 1024 + lane * 8;
    *(bf16x8*)o = *(bf16x8*)h8;
    *(bf16x8*)(o + 512) = *(bf16x8*)l8;
  }
}

// h = relu(x @ W_emb + b_emb) + pos_table[:n] -> packed u32 (fp32 compute, runs once)
__global__ __launch_bounds__(256) void k_embed(const float* __restrict__ x, const float* __restrict__ W,
                                               const float* __restrict__ bias, const float* __restrict__ pos,
                                               u32* __restrict__ hP) {
  __shared__ float xs[32][FEAT];
  const int t = threadIdx.x;
  const int row0 = blockIdx.x * 32;
  {
    const float4* xv = (const float4*)(x + (size_t)row0 * FEAT);
    float4* xd = (float4*)&xs[0][0];
    for (int i = t; i < 32 * FEAT / 4; i += 256) xd[i] = xv[i];
  }
  __syncthreads();
  const int c0 = (t & 31) * 4;
  const int r0 = (t >> 5) * 4;
  float acc[4][4] = {};
  #pragma unroll 2
  for (int k = 0; k < FEAT; k += 4) {
    float4 b0 = *(const float4*)&W[(k + 0) * HID + c0];
    float4 b1 = *(const float4*)&W[(k + 1) * HID + c0];
    float4 b2 = *(const float4*)&W[(k + 2) * HID + c0];
    float4 b3 = *(const float4*)&W[(k + 3) * HID + c0];
    float4 a0 = *(const float4*)&xs[r0 + 0][k];
    float4 a1 = *(const float4*)&xs[r0 + 1][k];
    float4 a2 = *(const float4*)&xs[r0 + 2][k];
    float4 a3 = *(const float4*)&xs[r0 + 3][k];
    micro4(a0, b0, b1, b2, b3, acc[0]);
    micro4(a1, b0, b1, b2, b3, acc[1]);
    micro4(a2, b0, b1, b2, b3, acc[2]);
    micro4(a3, b0, b1, b2, b3, acc[3]);
  }
  const float4 bv = *(const float4*)&bias[c0];
  #pragma unroll
  for (int r = 0; r < 4; ++r) {
    const int row = row0 + r0 + r;
    const int n = row & (NSEQ - 1);
    const float4 pv = *(const float4*)&pos[(size_t)n * HID + c0];
    uint4 pk;
    pk.x = pack_split(fmaxf(acc[r][0] + bv.x, 0.f) + pv.x);
    pk.y = pack_split(fmaxf(acc[r][1] + bv.y, 0.f) + pv.y);
    pk.z = pack_split(fmaxf(acc[r][2] + bv.z, 0.f) + pv.z);
    pk.w = pack_split(fmaxf(acc[r][3] + bv.w, 0.f) + pv.w);
    *(uint4*)&hP[(size_t)row * HID + c0] = pk;
  }
}

__global__ __launch_bounds__(256) void k_sinit(float* __restrict__ s) {
  const int i = blockIdx.x * 256 + threadIdx.x;
  if (i < RTOT) {
    const int n = i & (NSEQ - 1);
    s[(size_t)i * 3 + 0] = ((float)n - (NSEQ - 1) * 0.5f) / (float)NSEQ;
    s[(size_t)i * 3 + 1] = 0.f;
    s[(size_t)i * 3 + 2] = 0.f;
  }
}

// m = relu(h @ Wm + bm) -> FRAGMENT-BLOCKED bf16 planes for k_agg:
// mtB[b][jt(16)][nh(2)][nt(4)][plane(2)][64][8]
__global__ __launch_bounds__(512) void k_msg(const u32* __restrict__ hP, const short* __restrict__ wpl,
                                             int iter, const float* __restrict__ bm,
                                             short* __restrict__ mtB) {
  __shared__ short P[2][64][LDAP];   // h hi/lo planes
  __shared__ short T[2][128][72];    // transpose buffer [n][j-local]
  const int t = threadIdx.x;
  const int row0 = blockIdx.x * 64;
  stage_planes(hP + (size_t)row0 * HID, &P[0][0][0], &P[1][0][0], t);
  __syncthreads();
  const int l = t & 63, w = t >> 6;
  const int mt = w & 3, nh = w >> 2;
  const int lrow = mt * 16 + (l & 15);
  const int kgrp = (l >> 4) * 8;
  const int ncol = l & 15;
  f32x4 z4 = {0.f, 0.f, 0.f, 0.f};
  f32x4 acc[4];
  #pragma unroll
  for (int i = 0; i < 4; ++i) acc[i] = z4;
  GATE(acc, 0, wpl + (size_t)(0 * 3 + iter) * 32768);
  const int rbase = mt * 16 + (l >> 4) * 4;
  #pragma unroll
  for (int nt = 0; nt < 4; ++nt) {
    const int cc = nh * 64 + nt * 16 + ncol;
    const float bmc = bm[cc];
    #pragma unroll
    for (int q = 0; q < 4; ++q) {
      u32 pk = pack_split(fmaxf(acc[nt][q] + bmc, 0.f));
      T[0][cc][rbase + q] = (short)(pk >> 16);
      T[1][cc][rbase + q] = (short)(pk & 0xffff);
    }
  }
  __syncthreads();
  const int b = row0 >> 9, j0 = row0 & (NSEQ - 1);
  const int n = t >> 2, jq = (t & 3) * 16;
  const int nh2 = n >> 6, nt2 = (n >> 4) & 3;
  #pragma unroll
  for (int gch = 0; gch < 2; ++gch) {          // two 8-j groups
    const int jj = jq + gch * 8;               // 0..63 local
    const int jt = (j0 + jj) >> 5;             // global j-tile
    const int jjj = (j0 + jj) & 31;
    const int lane = (jjj >> 3) * 16 + (n & 15);
    #pragma unroll
    for (int pl = 0; pl < 2; ++pl) {
      size_t off = ((((((size_t)b * 16 + jt) * 2 + nh2) * 4 + nt2) * 2 + pl) * 64 + lane) * 8;
      *(bf16x8*)&mtB[off] = *(bf16x8*)&T[pl][n][jj];
    }
  }
}

// agg = (exp(-100 d2)*mask) @ m. Round-7 structure (LDS exp-tile, dbuf, shared
// exp work), i-tile reduced 32->16 so 2048 blocks -> 8 blocks/CU co-resident.
__global__ __launch_bounds__(256) void k_agg(const float* __restrict__ s, const float* __restrict__ mask,
                                             const short* __restrict__ mtB, u32* __restrict__ aggP) {
  __shared__ float sj[NSEQ][3];     // 6KB
  __shared__ short WH2[2][16][40];  // 2.5KB
  __shared__ short WL2[2][16][40];  // 2.5KB
  const int t = threadIdx.x;
  const int b = blockIdx.x;
  const int i0 = blockIdx.y * 16;
  {
    const float* sp = s + (size_t)b * NSEQ * 3;
    for (int i = t; i < NSEQ * 3; i += 256) (&sj[0][0])[i] = sp[i];
  }
  __syncthreads();
  const float* maskb = mask + (size_t)b * NSEQ * NSEQ;
  const int wi = t >> 4, wj2 = (t & 15) * 2;   // 16 rows x 32 j / 256 thr = 2/thread
  const float six = sj[i0 + wi][0], siy = sj[i0 + wi][1], siz = sj[i0 + wi][2];
  {  // slab 0 -> buf 0
    float2 mk = *(const float2*)&maskb[(size_t)(i0 + wi) * NSEQ + wj2];
    float vals[2] = {mk.x, mk.y};
    #pragma unroll
    for (int c = 0; c < 2; ++c) {
      const int jj = wj2 + c;
      float dx = six - sj[jj][0], dy = siy - sj[jj][1], dz = siz - sj[jj][2];
      u32 pk = pack_split(__expf(-100.0f * (dx * dx + dy * dy + dz * dz)) * vals[c]);
      WH2[0][wi][jj] = (short)(pk >> 16);
      WL2[0][wi][jj] = (short)(pk & 0xffff);
    }
  }
  __syncthreads();
  const int l = t & 63, w = t >> 6;
  const int nh = w & 1, ntp = w >> 1;          // wave covers nh half, nt pair
  const int kgrp = (l >> 4) * 8, ncol = l & 15;
  const int arow = l & 15;
  f32x4 z4 = {0.f, 0.f, 0.f, 0.f};
  f32x4 acc[2];
  acc[0] = z4; acc[1] = z4;
  const short* mtb = mtB + (size_t)b * 131072;
  #pragma unroll 1
  for (int jt = 0; jt < 16; ++jt) {
    const int buf = jt & 1;
    const int jn = (jt + 1) * 32;
    float2 mkn;
    if (jt < 15) mkn = *(const float2*)&maskb[(size_t)(i0 + wi) * NSEQ + jn + wj2];
    bf16x8 ah = *(bf16x8*)&WH2[buf][arow][kgrp];
    bf16x8 al = *(bf16x8*)&WL2[buf][arow][kgrp];
    #pragma unroll
    for (int ntl = 0; ntl < 2; ++ntl) {
      const int nt = ntp * 2 + ntl;
      const short* fb = mtb + ((((size_t)jt * 2 + nh) * 4 + nt) * 2) * 512 + l * 8;
      acc[ntl] = mfma3(ah, al, *(const bf16x8*)fb, *(const bf16x8*)(fb + 512), acc[ntl]);
    }
    if (jt < 15) {
      float vals[2] = {mkn.x, mkn.y};
      #pragma unroll
      for (int c = 0; c < 2; ++c) {
        const int jj = jn + wj2 + c;
        float dx = six - sj[jj][0], dy = siy - sj[jj][1], dz = siz - sj[jj][2];
        u32 pk = pack_split(__expf(-100.0f * (dx * dx + dy * dy + dz * dz)) * vals[c]);
        WH2[buf ^ 1][wi][wj2 + c] = (short)(pk >> 16);
        WL2[buf ^ 1][wi][wj2 + c] = (short)(pk & 0xffff);
      }
    }
    __syncthreads();
  }
  #pragma unroll
  for (int ntl = 0; ntl < 2; ++ntl) {
    const int cc = nh * 64 + (ntp * 2 + ntl) * 16 + ncol;
    #pragma unroll
    for (int q = 0; q < 4; ++q) {
      const int grow = i0 + (l >> 4) * 4 + q;
      aggP[((size_t)b * NSEQ + grow) * HID + cc] = pack_split(acc[ntl][q]);
    }
  }
}

// fused GRU + positional GRU: 6 gates, rh mid-kernel, then s-update in-kernel
// (h_new already on-chip -> no k_posgru dispatch, no h re-read).
__global__ __launch_bounds__(512) void k_zrc(
    const u32* __restrict__ aggP, u32* __restrict__ hP,
    const short* __restrict__ wpl, int iter,
    const float* __restrict__ bz, const float* __restrict__ br, const float* __restrict__ bhh,
    float* __restrict__ s,
    const float* __restrict__ Wpz, const float* __restrict__ Upz, const float* __restrict__ bpz,
    const float* __restrict__ Wpr, const float* __restrict__ Upr, const float* __restrict__ bpr,
    const float* __restrict__ Wph, const float* __restrict__ Uph, const float* __restrict__ bph) {
  __shared__ short P[4][64][LDAP];   // 0,1: agg hi/lo (later h_new hi/lo); 2,3: h hi/lo (later rh)
  const int t = threadIdx.x;
  const int row0 = blockIdx.x * 64;
  stage_planes(aggP + (size_t)row0 * HID, &P[0][0][0], &P[1][0][0], t);
  stage_planes(hP + (size_t)row0 * HID, &P[2][0][0], &P[3][0][0], t);
  __syncthreads();
  const int l = t & 63, w = t >> 6;
  const int mt = w & 3, nh = w >> 2;
  const int lrow = mt * 16 + (l & 15);
  const int kgrp = (l >> 4) * 8;
  const int ncol = l & 15;
  f32x4 z4 = {0.f, 0.f, 0.f, 0.f};
  f32x4 accz[4], accr[4];
  #pragma unroll
  for (int i = 0; i < 4; ++i) { accz[i] = z4; accr[i] = z4; }
  #pragma unroll 1
  for (int g = 0; g < 4; ++g) {   // Wz(agg), Uz(h), Wr(agg), Ur(h)
    const short* WB = wpl + (size_t)((g + 1) * 3 + iter) * 32768;
    const int ap = (g & 1) * 2;
    if (g < 2) { GATE(accz, ap, WB); }
    else       { GATE(accr, ap, WB); }
  }
  const int rbase = mt * 16 + (l >> 4) * 4;
  float hreg[4][4];
  float rhv[4][4];
  #pragma unroll
  for (int nt = 0; nt < 4; ++nt) {
    const int cc = nh * 64 + nt * 16 + ncol;
    const float brc = br[cc];
    #pragma unroll
    for (int q = 0; q < 4; ++q) {
      float hv = bf2f(P[2][rbase + q][cc]) + bf2f(P[3][rbase + q][cc]);
      hreg[nt][q] = hv;
      rhv[nt][q] = sigm(accr[nt][q] + brc) * hv;
    }
  }
  __syncthreads();   // all gates done reading h planes
  #pragma unroll
  for (int nt = 0; nt < 4; ++nt) {
    const int cc = nh * 64 + nt * 16 + ncol;
    #pragma unroll
    for (int q = 0; q < 4; ++q) {
      u32 pk = pack_split(rhv[nt][q]);
      P[2][rbase + q][cc] = (short)(pk >> 16);
      P[3][rbase + q][cc] = (short)(pk & 0xffff);
    }
  }
  __syncthreads();   // rh planes ready
  #pragma unroll
  for (int i = 0; i < 4; ++i) accr[i] = z4;   // reuse as cand accumulator
  GATE(accr, 0, wpl + (size_t)(5 * 3 + iter) * 32768);   // Wh (A=agg)
  GATE(accr, 2, wpl + (size_t)(6 * 3 + iter) * 32768);   // Uh (A=rh)
  float hn_[4][4];
  #pragma unroll
  for (int nt = 0; nt < 4; ++nt) {
    const int cc = nh * 64 + nt * 16 + ncol;
    const float bzc = bz[cc], bhc = bhh[cc];
    #pragma unroll
    for (int q = 0; q < 4; ++q) {
      float z = sigm(accz[nt][q] + bzc);
      float cand = tanh_fast(accr[nt][q] + bhc);
      float hn = (1.f - z) * hreg[nt][q] + z * cand;
      hn_[nt][q] = hn;
      hP[(size_t)(row0 + rbase + q) * HID + cc] = pack_split(hn);
    }
  }
  __syncthreads();   // all GATE reads of P[0/1] finished
  #pragma unroll
  for (int nt = 0; nt < 4; ++nt) {
    const int cc = nh * 64 + nt * 16 + ncol;
    #pragma unroll
    for (int q = 0; q < 4; ++q) {
      u32 pk = pack_split(hn_[nt][q]);
      P[0][rbase + q][cc] = (short)(pk >> 16);
      P[1][rbase + q][cc] = (short)(pk & 0xffff);
    }
  }
  __syncthreads();   // h_new planes ready
  // ---- positional GRU: 8 lanes per row, 16 dims each ----
  const int prow = t >> 3, sub = t & 7;
  float p[9] = {0.f, 0.f, 0.f, 0.f, 0.f, 0.f, 0.f, 0.f, 0.f};
  #pragma unroll 4
  for (int kk = 0; kk < 16; ++kk) {
    const int k = sub * 16 + kk;
    const float hv = bf2f(P[0][prow][k]) + bf2f(P[1][prow][k]);
    #pragma unroll
    for (int c = 0; c < 3; ++c) {
      p[c]     = fmaf(hv, Wpz[k * 3 + c], p[c]);
      p[3 + c] = fmaf(hv, Wpr[k * 3 + c], p[3 + c]);
      p[6 + c] = fmaf(hv, Wph[k * 3 + c], p[6 + c]);
    }
  }
  #pragma unroll
  for (int off = 1; off <= 4; off <<= 1) {
    #pragma unroll
    for (int q = 0; q < 9; ++q) p[q] += __shfl_xor(p[q], off, 64);
  }
  if (sub == 0) {
    const int row = row0 + prow;
    const float s0 = s[(size_t)row * 3 + 0], s1 = s[(size_t)row * 3 + 1], s2 = s[(size_t)row * 3 + 2];
    float zs[3], rs[3], ss[3];
    #pragma unroll
    for (int c = 0; c < 3; ++c) {
      zs[c] = sigm(p[c]     + s0 * Upz[c] + s1 * Upz[3 + c] + s2 * Upz[6 + c] + bpz[c]);
      rs[c] = sigm(p[3 + c] + s0 * Upr[c] + s1 * Upr[3 + c] + s2 * Upr[6 + c] + bpr[c]);
    }
    const float t0 = rs[0] * s0, t1 = rs[1] * s1, t2 = rs[2] * s2;
    #pragma unroll
    for (int c = 0; c < 3; ++c)
      ss[c] = tanh_fast(p[6 + c] + t0 * Uph[c] + t1 * Uph[3 + c] + t2 * Uph[6 + c] + bph[c]);
    s[(size_t)row * 3 + 0] = (1.f - zs[0]) * s0 + zs[0] * ss[0];
    s[(size_t)row * 3 + 1] = (1.f - zs[1]) * s1 + zs[1] * ss[1];
    s[(size_t)row * 3 + 2] = (1.f - zs[2]) * s2 + zs[2] * ss[2];
  }
}

// A[b,i,j] = exp(-100*||s_i-s_j||^2)*mask
__global__ __launch_bounds__(256) void k_finalA(const float* __restrict__ s, const float* __restrict__ mask,
                                                float* __restrict__ A) {
  __shared__ float sj[NSEQ][3];
  const int t = threadIdx.x;
  const int b = blockIdx.x;
  const int i0 = blockIdx.y * 16;
  {
    const float* sp = s + (size_t)b * NSEQ * 3;
    for (int i = t; i < NSEQ * 3; i += 256) (&sj[0][0])[i] = sp[i];
  }
  __syncthreads();
  #pragma unroll
  for (int p = 0; p < 8; ++p) {
    const int e = t + p * 256;
    const int ii = e >> 7;
    const int j4 = (e & 127) * 4;
    const float six = sj[i0 + ii][0], siy = sj[i0 + ii][1], siz = sj[i0 + ii][2];
    const size_t base = ((size_t)b * NSEQ + i0 + ii) * NSEQ + j4;
    const float4 mk = *(const float4*)&mask[base];
    float4 o;
    { float dx = six - sj[j4+0][0], dy = siy - sj[j4+0][1], dz = siz - sj[j4+0][2];
      o.x = __expf(-100.0f*(dx*dx + dy*dy + dz*dz)) * mk.x; }
    { float dx = six - sj[j4+1][0], dy = siy - sj[j4+1][1], dz = siz - sj[j4+1][2];
      o.y = __expf(-100.0f*(dx*dx + dy*dy + dz*dz)) * mk.y; }
    { float dx = six - sj[j4+2][0], dy = siy - sj[j4+2][1], dz = siz - sj[j4+2][2];
      o.z = __expf(-100.0f*(dx*dx + dy*dy + dz*dz)) * mk.z; }
    { float dx = six - sj[j4+3][0], dy = siy - sj[j4+3][1], dz = siz - sj[j4+3][2];
      o.w = __expf(-100.0f*(dx*dx + dy*dy + dz*dz)) * mk.w; }
    *(float4*)&A[base] = o;
  }
}

// ---------------- launcher ----------------

extern "C" void kernel_launch(void* const* d_in, const int* in_sizes, int n_in,
                              void* d_out, int out_size, void* d_ws, size_t ws_size,
                              hipStream_t stream) {
  const float* x      = (const float*)d_in[0];
  const float* mask   = (const float*)d_in[1];
  const float* W_emb  = (const float*)d_in[2];
  const float* b_emb  = (const float*)d_in[3];
  const float* pos    = (const float*)d_in[4];
  const float* Wm     = (const float*)d_in[5];
  const float* bm     = (const float*)d_in[6];
  const float* Wz     = (const float*)d_in[7];
  const float* Uz     = (const float*)d_in[8];
  const float* bz     = (const float*)d_in[9];
  const float* Wr     = (const float*)d_in[10];
  const float* Ur     = (const float*)d_in[11];
  const float* br     = (const float*)d_in[12];
  const float* Wh     = (const float*)d_in[13];
  const float* Uh     = (const float*)d_in[14];
  const float* bh     = (const float*)d_in[15];
  const float* Wpz    = (const float*)d_in[16];
  const float* Upz    = (const float*)d_in[17];
  const float* bpz    = (const float*)d_in[18];
  const float* Wpr    = (const float*)d_in[19];
  const float* Upr    = (const float*)d_in[20];
  const float* bpr    = (const float*)d_in[21];
  const float* Wph    = (const float*)d_in[22];
  const float* Uph    = (const float*)d_in[23];
  const float* bph    = (const float*)d_in[24];

  u32*   hP = (u32*)d_ws;
  float* s  = (float*)d_ws + (size_t)RTOT * HID;
  float* ob   = (float*)d_out;
  u32*   aggP = (u32*)ob;                                   // 16.8MB
  short* mtB  = (short*)(ob + (size_t)RTOT * HID);          // 16.8MB (blocked m)
  short* wpl  = mtB + (size_t)BSZ * 131072;                 // 1.4MB (blocked weights)

  k_prep<<<21, 256, 0, stream>>>(Wm, Wz, Uz, Wr, Ur, Wh, Uh, wpl);
  k_embed<<<RTOT / 32, 256, 0, stream>>>(x, W_emb, b_emb, pos, hP);
  k_sinit<<<RTOT / 256, 256, 0, stream>>>(s);

  for (int i = 0; i < NITER; ++i) {
    const size_t bo = (size_t)i * HID;
    k_msg<<<RTOT / 64, 512, 0, stream>>>(hP, wpl, i, bm + bo, mtB);
    k_agg<<<dim3(BSZ, NSEQ / 16), 256, 0, stream>>>(s, mask, mtB, aggP);
    k_zrc<<<RTOT / 64, 512, 0, stream>>>(aggP, hP, wpl, i, bz + bo, br + bo, bh + bo,
                                         s, Wpz, Upz, bpz, Wpr, Upr, bpr, Wph, Uph, bph);
  }
  k_finalA<<<dim3(BSZ, NSEQ / 16), 256, 0, stream>>>(s, mask, (float*)d_out);
}